// Round 5
// baseline (940.460 us; speedup 1.0000x reference)
//
#include <hip/hip_runtime.h>

// N=50000, E=600000, IN_CH=128, EDGE_DIM=64, OUT_CH=128
// edge_index delivered as int32.
//
// R5: barrier-free MFMA loops. A-frags straight from global bf16 (pre-converted
// ea/x), B-frags register-resident, indices via per-lane loads + __shfl, LDS
// only for the dst accumulator (ds_add_f32). No __syncthreads in any K-loop
// (R4 showed the vmcnt(0)+s_barrier drain serialized the whole kernel).

#define NB_SHIFT 5
#define BUCKET_NODES 32

typedef __bf16 bf16x8 __attribute__((ext_vector_type(8)));
typedef float  f32x4  __attribute__((ext_vector_type(4)));
typedef unsigned short ushort_t;
typedef unsigned int   uint_t;

__device__ __forceinline__ ushort_t f2b(float f) {   // RNE f32->bf16
    uint_t u = __float_as_uint(f);
    u += 0x7FFF + ((u >> 16) & 1);
    return (ushort_t)(u >> 16);
}
__device__ __forceinline__ uint_t pack2(float a, float b) {
    return (uint_t)f2b(a) | ((uint_t)f2b(b) << 16);
}

// ---------------------------------------------------------------------------
// K1: fold weights -> bf16 k-major tables + f32 bias.
//   WxmT16[c*128+k] = bf16( sum_j Wx[k][j]*Wm[j][c] )
//   WemT16[c*64 +k] = bf16( sum_j We[k][j]*Wm[128+j][c] )
// ---------------------------------------------------------------------------
__global__ void fuse_weights_kernel(const float* __restrict__ Wx,
                                    const float* __restrict__ bx,
                                    const float* __restrict__ We,
                                    const float* __restrict__ be,
                                    const float* __restrict__ Wm,
                                    const float* __restrict__ bm,
                                    ushort_t* __restrict__ WxmT16,
                                    ushort_t* __restrict__ WemT16,
                                    float* __restrict__ bf) {
    int idx = blockIdx.x * blockDim.x + threadIdx.x;
    if (idx < 128 * 128) {
        int r = idx >> 7, c = idx & 127;       // r=k, c=ch
        float acc = 0.f;
        #pragma unroll 8
        for (int j = 0; j < 128; ++j) acc += Wx[r * 128 + j] * Wm[j * 128 + c];
        WxmT16[c * 128 + r] = f2b(acc);
    } else if (idx < 128 * 128 + 64 * 128) {
        int t = idx - 128 * 128;
        int r = t >> 7, c = t & 127;           // r=k(<64), c=ch
        float acc = 0.f;
        #pragma unroll 8
        for (int j = 0; j < 128; ++j) acc += We[r * 128 + j] * Wm[(128 + j) * 128 + c];
        WemT16[c * 64 + r] = f2b(acc);
    } else if (idx < 128 * 128 + 64 * 128 + 128) {
        int c = idx - (128 * 128 + 64 * 128);
        float acc = bm[c];
        #pragma unroll 8
        for (int j = 0; j < 128; ++j)
            acc += bx[j] * Wm[j * 128 + c] + be[j] * Wm[(128 + j) * 128 + c];
        bf[c] = acc;
    }
}

// ---------------------------------------------------------------------------
// K2: stream-convert x and edge_attr to bf16 (row-major, 8 elems/thread).
// ---------------------------------------------------------------------------
__global__ void convert_kernel(const float* __restrict__ x,
                               const float* __restrict__ ea,
                               ushort_t* __restrict__ xb,
                               ushort_t* __restrict__ eab,
                               int nx8, int ne8) {
    int gid = blockIdx.x * blockDim.x + threadIdx.x;
    const float4* src; uint4* dst; size_t off;
    if (gid < nx8) {
        src = (const float4*)x;  dst = (uint4*)xb;  off = (size_t)gid * 2;
    } else if (gid < nx8 + ne8) {
        int g = gid - nx8;
        src = (const float4*)ea; dst = (uint4*)eab; off = (size_t)g * 2;
        gid = g;
    } else return;
    float4 v0 = src[off], v1 = src[off + 1];
    uint4 w;
    w.x = pack2(v0.x, v0.y);
    w.y = pack2(v0.z, v0.w);
    w.z = pack2(v1.x, v1.y);
    w.w = pack2(v1.z, v1.w);
    dst[gid] = w;
}

// ---------------------------------------------------------------------------
// K3: u = xb @ WxmT16 + bf  (bf16 MFMA, no LDS, no barriers).
// One wave = 16 nodes x 64 channels; K=128 (4 MFMA steps x 4 ct tiles).
// ---------------------------------------------------------------------------
__global__ __launch_bounds__(256) void node_gemm_kernel(
        const ushort_t* __restrict__ xb, const ushort_t* __restrict__ WxmT16,
        const float* __restrict__ bf, float* __restrict__ u, int N) {
    int tid = threadIdx.x;
    int g = blockIdx.x * 4 + (tid >> 6);   // global wave id
    if (g >= (N / 16) * 2) return;         // N = 50000 = 16*3125
    int lane = tid & 63, l15 = lane & 15, quad = lane >> 4;
    int n0 = (g >> 1) * 16;
    int chBase = (g & 1) * 64;

    bf16x8 B[4][4];   // [ct][kk]
    #pragma unroll
    for (int ct = 0; ct < 4; ++ct)
        #pragma unroll
        for (int kk = 0; kk < 4; ++kk)
            B[ct][kk] = __builtin_bit_cast(bf16x8, *((const uint4*)
                &WxmT16[(size_t)(chBase + ct * 16 + l15) * 128 + kk * 32 + quad * 8]));

    bf16x8 A[4];
    #pragma unroll
    for (int kk = 0; kk < 4; ++kk)
        A[kk] = __builtin_bit_cast(bf16x8, *((const uint4*)
            &xb[(size_t)(n0 + l15) * 128 + kk * 32 + quad * 8]));

    f32x4 acc[4] = {{0.f,0.f,0.f,0.f},{0.f,0.f,0.f,0.f},
                    {0.f,0.f,0.f,0.f},{0.f,0.f,0.f,0.f}};
    #pragma unroll
    for (int kk = 0; kk < 4; ++kk)
        #pragma unroll
        for (int ct = 0; ct < 4; ++ct)
            acc[ct] = __builtin_amdgcn_mfma_f32_16x16x32_bf16(A[kk], B[ct][kk], acc[ct], 0, 0, 0);

    #pragma unroll
    for (int ct = 0; ct < 4; ++ct) {
        float bias = bf[chBase + ct * 16 + l15];
        #pragma unroll
        for (int r = 0; r < 4; ++r)
            u[(size_t)(n0 + quad * 4 + r) * 128 + chBase + ct * 16 + l15] = acc[ct][r] + bias;
    }
}

// ---------------------------------------------------------------------------
// counting sort by destination bucket (unchanged from R3/R4)
// ---------------------------------------------------------------------------
__global__ void hist_kernel(const int* __restrict__ ei, int* __restrict__ cnt, int E) {
    int e = blockIdx.x * blockDim.x + threadIdx.x;
    if (e < E) atomicAdd(&cnt[ei[E + e] >> NB_SHIFT], 1);
}

__global__ __launch_bounds__(1024) void scan_kernel(
        const int* __restrict__ cnt, int* __restrict__ start,
        int* __restrict__ cur, int nb, int E) {
    __shared__ int s[2048];
    int t = threadIdx.x;
    s[t]        = (t < nb)        ? cnt[t]        : 0;
    s[t + 1024] = (t + 1024 < nb) ? cnt[t + 1024] : 0;
    for (int d = 1; d < 2048; d <<= 1) {
        __syncthreads();
        int idx = (t + 1) * (d << 1) - 1;
        if (idx < 2048) s[idx] += s[idx - d];
    }
    __syncthreads();
    if (t == 0) s[2047] = 0;
    for (int d = 1024; d >= 1; d >>= 1) {
        __syncthreads();
        int idx = (t + 1) * (d << 1) - 1;
        if (idx < 2048) { int tmp = s[idx - d]; s[idx - d] = s[idx]; s[idx] += tmp; }
    }
    __syncthreads();
    if (t < nb)        { start[t] = s[t];               cur[t] = s[t]; }
    if (t + 1024 < nb) { start[t + 1024] = s[t + 1024]; cur[t + 1024] = s[t + 1024]; }
    if (t == 0) start[nb] = E;
}

__global__ void scatter_kernel(const int* __restrict__ ei, int* __restrict__ cur,
                               int* __restrict__ sorted, int E) {
    int e = blockIdx.x * blockDim.x + threadIdx.x;
    if (e < E) {
        int b = ei[E + e] >> NB_SHIFT;
        int pos = atomicAdd(&cur[b], 1);
        sorted[pos] = e;
    }
}

// ---------------------------------------------------------------------------
// K4: per-bucket MFMA edge GEMM, barrier-free K-loop.
// Wave w: edge chunks t = s0+(w&1)*16, +32, ...; channels (w>>1)*64.
// LDS: accum 16.9 KB only. Two barriers total (after zero, before readout).
// ---------------------------------------------------------------------------
__global__ __launch_bounds__(256, 4) void edge_bucket_kernel(
        const ushort_t* __restrict__ eab, const int* __restrict__ ei,
        const ushort_t* __restrict__ WemT16, const float* __restrict__ u,
        const int* __restrict__ start, const int* __restrict__ sorted,
        const float* __restrict__ beta, float* __restrict__ out,
        int E, int N) {
    __shared__ __align__(16) float accum[32 * 132];

    int tid = threadIdx.x;
    int b = blockIdx.x;
    int base = b << NB_SHIFT;

    for (int li = tid; li < 32 * 132; li += 256) accum[li] = 0.f;

    int lane = tid & 63, w = tid >> 6;
    int l15 = lane & 15, quad = lane >> 4;
    int chBase = (w >> 1) << 6;

    // B-fragments: register-resident for the whole kernel
    bf16x8 B[4][2];   // [ct][kk]
    #pragma unroll
    for (int ct = 0; ct < 4; ++ct)
        #pragma unroll
        for (int kk = 0; kk < 2; ++kk)
            B[ct][kk] = __builtin_bit_cast(bf16x8, *((const uint4*)
                &WemT16[(size_t)(chBase + ct * 16 + l15) * 64 + kk * 32 + quad * 8]));

    __syncthreads();   // accum zeroed

    int s0 = start[b], s1 = start[b + 1];

    for (int t = s0 + ((w & 1) << 4); t < s1; t += 32) {
        int m = s1 - t; if (m > 16) m = 16;
        int row = l15 < m ? l15 : m - 1;

        int e   = sorted[t + row];
        int src = ei[e];
        int dst = ei[E + e] - base;

        // A-fragments straight from global bf16
        bf16x8 a0 = __builtin_bit_cast(bf16x8, *((const uint4*)&eab[(size_t)e * 64 + quad * 8]));
        bf16x8 a1 = __builtin_bit_cast(bf16x8, *((const uint4*)&eab[(size_t)e * 64 + 32 + quad * 8]));

        // per-row src/dst via shfl; prefetch u before MFMA
        int sr[4], dr[4];
        float uv[4][4];
        #pragma unroll
        for (int r = 0; r < 4; ++r) {
            int mm = quad * 4 + r;
            sr[r] = __shfl(src, mm);
            dr[r] = __shfl(dst, mm);
            if (mm < m) {
                #pragma unroll
                for (int ct = 0; ct < 4; ++ct)
                    uv[ct][r] = u[(size_t)sr[r] * 128 + chBase + ct * 16 + l15];
            }
        }

        f32x4 acc[4] = {{0.f,0.f,0.f,0.f},{0.f,0.f,0.f,0.f},
                        {0.f,0.f,0.f,0.f},{0.f,0.f,0.f,0.f}};
        #pragma unroll
        for (int ct = 0; ct < 4; ++ct)
            acc[ct] = __builtin_amdgcn_mfma_f32_16x16x32_bf16(a0, B[ct][0], acc[ct], 0, 0, 0);
        #pragma unroll
        for (int ct = 0; ct < 4; ++ct)
            acc[ct] = __builtin_amdgcn_mfma_f32_16x16x32_bf16(a1, B[ct][1], acc[ct], 0, 0, 0);

        #pragma unroll
        for (int r = 0; r < 4; ++r) {
            int mm = quad * 4 + r;
            if (mm < m) {
                #pragma unroll
                for (int ct = 0; ct < 4; ++ct) {
                    float msg = acc[ct][r] + uv[ct][r];
                    msg = msg > 0.f ? msg : 0.01f * msg;
                    atomicAdd(&accum[dr[r] * 132 + chBase + ct * 16 + l15], msg);
                }
            }
        }
    }
    __syncthreads();

    // fused finalize: sigmoid(agg) * relu(beta)
    float rb = beta[0];
    rb = rb > 0.f ? rb : 0.f;
    #pragma unroll
    for (int i = 0; i < 4; ++i) {
        int li = tid + i * 256;
        int r = li >> 5, c4 = li & 31;
        int n = base + r;
        if (n < N) {
            float4 v = *((float4*)&accum[r * 132 + c4 * 4]);
            v.x = rb / (1.f + __expf(-v.x));
            v.y = rb / (1.f + __expf(-v.y));
            v.z = rb / (1.f + __expf(-v.z));
            v.w = rb / (1.f + __expf(-v.w));
            ((float4*)out)[(size_t)n * 32 + c4] = v;
        }
    }
}

// ---------------------------------------------------------------------------
extern "C" void kernel_launch(void* const* d_in, const int* in_sizes, int n_in,
                              void* d_out, int out_size, void* d_ws, size_t ws_size,
                              hipStream_t stream) {
    const float* x    = (const float*)d_in[0];
    const int*   ei   = (const int*)d_in[1];
    const float* ea   = (const float*)d_in[2];
    const float* Wx   = (const float*)d_in[3];
    const float* bx   = (const float*)d_in[4];
    const float* We   = (const float*)d_in[5];
    const float* be   = (const float*)d_in[6];
    const float* Wm   = (const float*)d_in[7];
    const float* bm   = (const float*)d_in[8];
    const float* beta = (const float*)d_in[9];

    int N = in_sizes[0] / 128;   // 50000
    int E = in_sizes[2] / 64;    // 600000
    int nb = (N + BUCKET_NODES - 1) >> NB_SHIFT;   // 1563

    float* out = (float*)d_out;

    // workspace layout (bytes)
    char* ws = (char*)d_ws;
    ushort_t* WxmT16 = (ushort_t*)(ws);                    // 32768
    ushort_t* WemT16 = (ushort_t*)(ws + 32768);            // 16384
    float*    bf     = (float*)(ws + 49152);               // 512
    float*    u      = (float*)(ws + 65536);               // 25.6 MB
    size_t off = 65536 + (size_t)N * 128 * 4;
    ushort_t* xb  = (ushort_t*)(ws + off);                 // 12.8 MB
    off += (size_t)N * 128 * 2;
    ushort_t* eab = (ushort_t*)(ws + off);                 // 76.8 MB
    off += (size_t)E * 64 * 2;
    int* cnt    = (int*)(ws + off);
    int* startb = (int*)(ws + off + 8192);
    int* cur    = (int*)(ws + off + 16384);
    int* sorted = (int*)(ws + off + 24576);                // E ints

    hipMemsetAsync(cnt, 0, (size_t)nb * sizeof(int), stream);

    fuse_weights_kernel<<<(24704 + 255) / 256, 256, 0, stream>>>(
        Wx, bx, We, be, Wm, bm, WxmT16, WemT16, bf);

    int nx8 = N * 128 / 8;       // 800000
    int ne8 = E * 64 / 8;        // 4800000
    convert_kernel<<<(nx8 + ne8 + 255) / 256, 256, 0, stream>>>(
        x, ea, xb, eab, nx8, ne8);

    node_gemm_kernel<<<(N / 16 * 2 + 3) / 4, 256, 0, stream>>>(
        xb, WxmT16, bf, u, N);

    hist_kernel<<<(E + 255) / 256, 256, 0, stream>>>(ei, cnt, E);
    scan_kernel<<<1, 1024, 0, stream>>>(cnt, startb, cur, nb, E);
    scatter_kernel<<<(E + 255) / 256, 256, 0, stream>>>(ei, cur, sorted, E);

    edge_bucket_kernel<<<nb, 256, 0, stream>>>(
        eab, ei, WemT16, u, startb, sorted, beta, out, E, N);
}

// Round 6
// 748.334 us; speedup vs baseline: 1.2567x; 1.2567x over previous
//
#include <hip/hip_runtime.h>

// N=50000, E=600000, IN_CH=128, EDGE_DIM=64, OUT_CH=128
// edge_index delivered as int32.
//
// R6: the edge kernel streams SORTED edge data (recs + eabs written in sorted
// order by the binning passes) -> every address in the hot loop is
// loop-computable except the u-gather, whose index comes from one prefetched
// 4B record. 16-node buckets (3125 blocks). Sort uses LDS-binned histogram +
// block rank-and-reserve (~230k global atomics vs R5's 1.2M).

#define NB 3125
#define NB_SHIFT 4

typedef __bf16 bf16x8 __attribute__((ext_vector_type(8)));
typedef float  f32x4  __attribute__((ext_vector_type(4)));
typedef unsigned short ushort_t;
typedef unsigned int   uint_t;

__device__ __forceinline__ ushort_t f2b(float f) {   // RNE f32->bf16
    uint_t u = __float_as_uint(f);
    u += 0x7FFF + ((u >> 16) & 1);
    return (ushort_t)(u >> 16);
}
__device__ __forceinline__ uint_t pack2(float a, float b) {
    return (uint_t)f2b(a) | ((uint_t)f2b(b) << 16);
}

// ---------------------------------------------------------------------------
// K1: fold weights -> bf16 k-major tables + f32 bias.
// ---------------------------------------------------------------------------
__global__ void fuse_weights_kernel(const float* __restrict__ Wx,
                                    const float* __restrict__ bx,
                                    const float* __restrict__ We,
                                    const float* __restrict__ be,
                                    const float* __restrict__ Wm,
                                    const float* __restrict__ bm,
                                    ushort_t* __restrict__ WxmT16,
                                    ushort_t* __restrict__ WemT16,
                                    float* __restrict__ bf) {
    int idx = blockIdx.x * blockDim.x + threadIdx.x;
    if (idx < 128 * 128) {
        int r = idx >> 7, c = idx & 127;       // r=k, c=ch
        float acc = 0.f;
        #pragma unroll 8
        for (int j = 0; j < 128; ++j) acc += Wx[r * 128 + j] * Wm[j * 128 + c];
        WxmT16[c * 128 + r] = f2b(acc);
    } else if (idx < 128 * 128 + 64 * 128) {
        int t = idx - 128 * 128;
        int r = t >> 7, c = t & 127;           // r=k(<64), c=ch
        float acc = 0.f;
        #pragma unroll 8
        for (int j = 0; j < 128; ++j) acc += We[r * 128 + j] * Wm[(128 + j) * 128 + c];
        WemT16[c * 64 + r] = f2b(acc);
    } else if (idx < 128 * 128 + 64 * 128 + 128) {
        int c = idx - (128 * 128 + 64 * 128);
        float acc = bm[c];
        #pragma unroll 8
        for (int j = 0; j < 128; ++j)
            acc += bx[j] * Wm[j * 128 + c] + be[j] * Wm[(128 + j) * 128 + c];
        bf[c] = acc;
    }
}

// ---------------------------------------------------------------------------
// K2: stream-convert x to bf16.
// ---------------------------------------------------------------------------
__global__ void convert_x_kernel(const float* __restrict__ x,
                                 ushort_t* __restrict__ xb, int nx8) {
    int gid = blockIdx.x * blockDim.x + threadIdx.x;
    if (gid >= nx8) return;
    const float4* s = (const float4*)x + (size_t)gid * 2;
    float4 v0 = s[0], v1 = s[1];
    uint4 w;
    w.x = pack2(v0.x, v0.y);
    w.y = pack2(v0.z, v0.w);
    w.z = pack2(v1.x, v1.y);
    w.w = pack2(v1.z, v1.w);
    ((uint4*)xb)[gid] = w;
}

// ---------------------------------------------------------------------------
// K3: u = xb @ WxmT16 + bf  (bf16 MFMA, no LDS, no barriers).
// ---------------------------------------------------------------------------
__global__ __launch_bounds__(256) void node_gemm_kernel(
        const ushort_t* __restrict__ xb, const ushort_t* __restrict__ WxmT16,
        const float* __restrict__ bf, float* __restrict__ u, int N) {
    int tid = threadIdx.x;
    int g = blockIdx.x * 4 + (tid >> 6);
    if (g >= (N / 16) * 2) return;
    int lane = tid & 63, l15 = lane & 15, quad = lane >> 4;
    int n0 = (g >> 1) * 16;
    int chBase = (g & 1) * 64;

    bf16x8 B[4][4];
    #pragma unroll
    for (int ct = 0; ct < 4; ++ct)
        #pragma unroll
        for (int kk = 0; kk < 4; ++kk)
            B[ct][kk] = __builtin_bit_cast(bf16x8, *((const uint4*)
                &WxmT16[(size_t)(chBase + ct * 16 + l15) * 128 + kk * 32 + quad * 8]));

    bf16x8 A[4];
    #pragma unroll
    for (int kk = 0; kk < 4; ++kk)
        A[kk] = __builtin_bit_cast(bf16x8, *((const uint4*)
            &xb[(size_t)(n0 + l15) * 128 + kk * 32 + quad * 8]));

    f32x4 acc[4] = {{0.f,0.f,0.f,0.f},{0.f,0.f,0.f,0.f},
                    {0.f,0.f,0.f,0.f},{0.f,0.f,0.f,0.f}};
    #pragma unroll
    for (int kk = 0; kk < 4; ++kk)
        #pragma unroll
        for (int ct = 0; ct < 4; ++ct)
            acc[ct] = __builtin_amdgcn_mfma_f32_16x16x32_bf16(A[kk], B[ct][kk], acc[ct], 0, 0, 0);

    #pragma unroll
    for (int ct = 0; ct < 4; ++ct) {
        float bias = bf[chBase + ct * 16 + l15];
        #pragma unroll
        for (int r = 0; r < 4; ++r)
            u[(size_t)(n0 + quad * 4 + r) * 128 + chBase + ct * 16 + l15] = acc[ct][r] + bias;
    }
}

// ---------------------------------------------------------------------------
// K4: LDS-binned histogram of dst buckets.
// ---------------------------------------------------------------------------
__global__ __launch_bounds__(1024) void hist_kernel(
        const int* __restrict__ ei, int* __restrict__ cnt, int E) {
    __shared__ int lcnt[NB];
    int t = threadIdx.x;
    for (int i = t; i < NB; i += 1024) lcnt[i] = 0;
    __syncthreads();
    int base = blockIdx.x * 8192;
    #pragma unroll
    for (int j = 0; j < 8; ++j) {
        int e = base + t + j * 1024;
        if (e < E) atomicAdd(&lcnt[ei[E + e] >> NB_SHIFT], 1);
    }
    __syncthreads();
    for (int i = t; i < NB; i += 1024) {
        int c = lcnt[i];
        if (c) atomicAdd(&cnt[i], c);
    }
}

// ---------------------------------------------------------------------------
// K5: exclusive scan of cnt -> start, cur. Single block, 4 elems/thread.
// ---------------------------------------------------------------------------
__global__ __launch_bounds__(1024) void scan_kernel(
        const int* __restrict__ cnt, int* __restrict__ start,
        int* __restrict__ cur, int nb, int E) {
    __shared__ int tot[1024];
    int t = threadIdx.x;
    int v[4]; int sum = 0;
    #pragma unroll
    for (int j = 0; j < 4; ++j) {
        int i = t * 4 + j;
        v[j] = (i < nb) ? cnt[i] : 0;
        sum += v[j];
    }
    tot[t] = sum;
    __syncthreads();
    for (int d = 1; d < 1024; d <<= 1) {
        int val = tot[t];
        int add = (t >= d) ? tot[t - d] : 0;
        __syncthreads();
        tot[t] = val + add;
        __syncthreads();
    }
    int ex = (t == 0) ? 0 : tot[t - 1];
    #pragma unroll
    for (int j = 0; j < 4; ++j) {
        int i = t * 4 + j;
        if (i < nb) { start[i] = ex; cur[i] = ex; }
        ex += v[j];
    }
    if (t == 1023) start[nb] = ex;   // == E
}

// ---------------------------------------------------------------------------
// K6: block rank-and-reserve binning: pos[e], recs[pos] = src | dstl<<16.
// ---------------------------------------------------------------------------
__global__ __launch_bounds__(1024) void binpos_kernel(
        const int* __restrict__ ei, int* __restrict__ cur,
        int* __restrict__ pos, uint_t* __restrict__ recs, int E) {
    __shared__ int lcnt[NB];
    __shared__ int lbase[NB];
    int t = threadIdx.x;
    for (int i = t; i < NB; i += 1024) lcnt[i] = 0;
    __syncthreads();
    int base = blockIdx.x * 8192;
    int myrank[8], mybkt[8];
    #pragma unroll
    for (int j = 0; j < 8; ++j) {
        int e = base + t + j * 1024;
        if (e < E) {
            int b = ei[E + e] >> NB_SHIFT;
            mybkt[j] = b;
            myrank[j] = atomicAdd(&lcnt[b], 1);
        }
    }
    __syncthreads();
    for (int i = t; i < NB; i += 1024) {
        int c = lcnt[i];
        lbase[i] = c ? atomicAdd(&cur[i], c) : 0;
    }
    __syncthreads();
    #pragma unroll
    for (int j = 0; j < 8; ++j) {
        int e = base + t + j * 1024;
        if (e < E) {
            int p = lbase[mybkt[j]] + myrank[j];
            pos[e] = p;
            uint_t src  = (uint_t)ei[e];                 // < 65536
            uint_t dstl = (uint_t)(ei[E + e] & (  (1 << NB_SHIFT) - 1));
            recs[p] = src | (dstl << 16);
        }
    }
}

// ---------------------------------------------------------------------------
// K7: copy ea rows (f32) to eabs (bf16) in sorted order. 8 lanes per row.
// ---------------------------------------------------------------------------
__global__ void copy_ea_kernel(const float* __restrict__ ea,
                               const int* __restrict__ pos,
                               ushort_t* __restrict__ eabs, int E8) {
    int gid = blockIdx.x * blockDim.x + threadIdx.x;
    if (gid >= E8) return;
    int e = gid >> 3, seg = gid & 7;
    int p = pos[e];
    const float4* s = (const float4*)ea + (size_t)e * 16 + seg * 2;
    float4 v0 = s[0], v1 = s[1];
    uint4 w;
    w.x = pack2(v0.x, v0.y);
    w.y = pack2(v0.z, v0.w);
    w.z = pack2(v1.x, v1.y);
    w.w = pack2(v1.z, v1.w);
    *((uint4*)&eabs[(size_t)p * 64 + seg * 8]) = w;
}

// ---------------------------------------------------------------------------
// K8: per-bucket MFMA edge GEMM over SORTED streams; only u-gather is random.
// 4 waves: (w&1) edge-tile offset, (w>>1) channel half. Barrier-free K-loop.
// ---------------------------------------------------------------------------
__global__ __launch_bounds__(256, 4) void edge_bucket_kernel(
        const ushort_t* __restrict__ eabs, const uint_t* __restrict__ recs,
        const ushort_t* __restrict__ WemT16, const float* __restrict__ u,
        const int* __restrict__ start, const float* __restrict__ beta,
        float* __restrict__ out, int N) {
    __shared__ __align__(16) float accum[16 * 132];   // 8448 B

    int tid = threadIdx.x;
    int b = blockIdx.x;
    int base = b << NB_SHIFT;

    for (int li = tid; li < 16 * 132; li += 256) accum[li] = 0.f;

    int lane = tid & 63, w = tid >> 6;
    int l15 = lane & 15, quad = lane >> 4;
    int chBase = (w >> 1) << 6;

    bf16x8 B[4][2];
    #pragma unroll
    for (int ct = 0; ct < 4; ++ct)
        #pragma unroll
        for (int kk = 0; kk < 2; ++kk)
            B[ct][kk] = __builtin_bit_cast(bf16x8, *((const uint4*)
                &WemT16[(size_t)(chBase + ct * 16 + l15) * 64 + kk * 32 + quad * 8]));

    __syncthreads();   // accum zeroed

    int s0 = start[b], s1 = start[b + 1];
    int t = s0 + ((w & 1) << 4);

    if (t < s1) {
        int m = s1 - t; if (m > 16) m = 16;
        int row = l15 < m ? l15 : m - 1;
        uint_t rec = recs[t + row];
        bf16x8 a0 = __builtin_bit_cast(bf16x8,
            *((const uint4*)&eabs[(size_t)(t + row) * 64 + quad * 8]));
        bf16x8 a1 = __builtin_bit_cast(bf16x8,
            *((const uint4*)&eabs[(size_t)(t + row) * 64 + 32 + quad * 8]));

        while (t < s1) {
            // software-prefetch next tile (addresses loop-computable)
            int tn = t + 32;
            uint_t recn = 0;
            bf16x8 a0n = a0, a1n = a1;
            int mn = 0;
            if (tn < s1) {
                mn = s1 - tn; if (mn > 16) mn = 16;
                int rown = l15 < mn ? l15 : mn - 1;
                recn = recs[tn + rown];
                a0n = __builtin_bit_cast(bf16x8,
                    *((const uint4*)&eabs[(size_t)(tn + rown) * 64 + quad * 8]));
                a1n = __builtin_bit_cast(bf16x8,
                    *((const uint4*)&eabs[(size_t)(tn + rown) * 64 + 32 + quad * 8]));
            }

            // u-gather (index from prefetched rec -> issues immediately)
            int dr[4]; float uv[4][4];
            #pragma unroll
            for (int r = 0; r < 4; ++r) {
                int mm = quad * 4 + r;
                uint_t rr = __shfl(rec, mm);
                int sr = rr & 0xFFFF;
                dr[r] = rr >> 16;
                if (mm < m) {
                    #pragma unroll
                    for (int ct = 0; ct < 4; ++ct)
                        uv[ct][r] = u[(size_t)sr * 128 + chBase + ct * 16 + l15];
                }
            }

            f32x4 acc[4] = {{0.f,0.f,0.f,0.f},{0.f,0.f,0.f,0.f},
                            {0.f,0.f,0.f,0.f},{0.f,0.f,0.f,0.f}};
            #pragma unroll
            for (int ct = 0; ct < 4; ++ct)
                acc[ct] = __builtin_amdgcn_mfma_f32_16x16x32_bf16(a0, B[ct][0], acc[ct], 0, 0, 0);
            #pragma unroll
            for (int ct = 0; ct < 4; ++ct)
                acc[ct] = __builtin_amdgcn_mfma_f32_16x16x32_bf16(a1, B[ct][1], acc[ct], 0, 0, 0);

            #pragma unroll
            for (int r = 0; r < 4; ++r) {
                int mm = quad * 4 + r;
                if (mm < m) {
                    #pragma unroll
                    for (int ct = 0; ct < 4; ++ct) {
                        float msg = acc[ct][r] + uv[ct][r];
                        msg = msg > 0.f ? msg : 0.01f * msg;
                        atomicAdd(&accum[dr[r] * 132 + chBase + ct * 16 + l15], msg);
                    }
                }
            }

            t = tn; m = mn; rec = recn; a0 = a0n; a1 = a1n;
        }
    }
    __syncthreads();

    // fused finalize: sigmoid(agg) * relu(beta)
    float rb = beta[0];
    rb = rb > 0.f ? rb : 0.f;
    #pragma unroll
    for (int i = 0; i < 2; ++i) {
        int li = tid + i * 256;        // 0..511
        int r = li >> 5, c4 = li & 31;
        int n = base + r;
        if (n < N) {
            float4 v = *((float4*)&accum[r * 132 + c4 * 4]);
            v.x = rb / (1.f + __expf(-v.x));
            v.y = rb / (1.f + __expf(-v.y));
            v.z = rb / (1.f + __expf(-v.z));
            v.w = rb / (1.f + __expf(-v.w));
            ((float4*)out)[(size_t)n * 32 + c4] = v;
        }
    }
}

// ---------------------------------------------------------------------------
extern "C" void kernel_launch(void* const* d_in, const int* in_sizes, int n_in,
                              void* d_out, int out_size, void* d_ws, size_t ws_size,
                              hipStream_t stream) {
    const float* x    = (const float*)d_in[0];
    const int*   ei   = (const int*)d_in[1];
    const float* ea   = (const float*)d_in[2];
    const float* Wx   = (const float*)d_in[3];
    const float* bx   = (const float*)d_in[4];
    const float* We   = (const float*)d_in[5];
    const float* be   = (const float*)d_in[6];
    const float* Wm   = (const float*)d_in[7];
    const float* bm   = (const float*)d_in[8];
    const float* beta = (const float*)d_in[9];

    int N = in_sizes[0] / 128;   // 50000
    int E = in_sizes[2] / 64;    // 600000

    float* out = (float*)d_out;

    // workspace layout (bytes)
    char* ws = (char*)d_ws;
    ushort_t* WxmT16 = (ushort_t*)(ws);                    // 32768
    ushort_t* WemT16 = (ushort_t*)(ws + 32768);            // 16384
    float*    bf     = (float*)(ws + 49152);               // 512
    float*    u      = (float*)(ws + 65536);               // 25.6 MB
    size_t off = 65536 + (size_t)N * 128 * 4;
    ushort_t* xb   = (ushort_t*)(ws + off);                // 12.8 MB
    off += (size_t)N * 128 * 2;
    ushort_t* eabs = (ushort_t*)(ws + off);                // 76.8 MB
    off += (size_t)E * 64 * 2;
    uint_t* recs   = (uint_t*)(ws + off);                  // 2.4 MB
    off += (size_t)E * 4;
    int* pos       = (int*)(ws + off);                     // 2.4 MB
    off += (size_t)E * 4;
    int* cnt       = (int*)(ws + off);                     // NB ints
    int* startb    = (int*)(ws + off + 16384);             // NB+1 ints
    int* cur       = (int*)(ws + off + 32768);             // NB ints

    hipMemsetAsync(cnt, 0, (size_t)NB * sizeof(int), stream);

    fuse_weights_kernel<<<(24704 + 255) / 256, 256, 0, stream>>>(
        Wx, bx, We, be, Wm, bm, WxmT16, WemT16, bf);

    int nx8 = N * 128 / 8;   // 800000
    convert_x_kernel<<<(nx8 + 255) / 256, 256, 0, stream>>>(x, xb, nx8);

    node_gemm_kernel<<<(N / 16 * 2 + 3) / 4, 256, 0, stream>>>(
        xb, WxmT16, bf, u, N);

    int nbBlocks = (E + 8191) / 8192;   // 74
    hist_kernel<<<nbBlocks, 1024, 0, stream>>>(ei, cnt, E);
    scan_kernel<<<1, 1024, 0, stream>>>(cnt, startb, cur, NB, E);
    binpos_kernel<<<nbBlocks, 1024, 0, stream>>>(ei, cur, pos, recs, E);

    int E8 = E * 8;   // 4.8M
    copy_ea_kernel<<<(E8 + 255) / 256, 256, 0, stream>>>(ea, pos, eabs, E8);

    edge_bucket_kernel<<<NB, 256, 0, stream>>>(
        eabs, recs, WemT16, u, startb, beta, out, N);
}